// Round 1
// baseline (232.567 us; speedup 1.0000x reference)
//
#include <hip/hip_runtime.h>
#include <hip/hip_bf16.h>
#include <stdint.h>

typedef __attribute__((ext_vector_type(8))) short short8;
typedef __attribute__((ext_vector_type(4))) float f32x4;
typedef __attribute__((ext_vector_type(4))) float fvec4;
typedef __attribute__((ext_vector_type(4))) unsigned short us4;

#define DEV static __device__ __forceinline__

constexpr int Hn = 1024;
constexpr int Bn = 4;
constexpr int Sn = 2048;
constexpr float SCALE_F = 0.03125f;           // 1/sqrt(1024)
constexpr float LOG2E_F = 1.4426950408889634f;

DEV unsigned short f2bf(float f) {
  union { float f; unsigned u; } c; c.f = f;
  unsigned r = c.u + 0x7fffu + ((c.u >> 16) & 1u);   // RNE
  return (unsigned short)(r >> 16);
}

DEV void gload16(void* g, void* l) {
  __builtin_amdgcn_global_load_lds(
      (__attribute__((address_space(1))) void*)g,
      (__attribute__((address_space(3))) void*)l, 16, 0, 0);
}

// ---------------- fp32 -> bf16 convert (x, wq, wk, wv) ----------------
__global__ __launch_bounds__(256) void cvt_kernel(
    const float* __restrict__ x, const float* __restrict__ wq,
    const float* __restrict__ wk, const float* __restrict__ wv,
    unsigned short* __restrict__ xb, unsigned short* __restrict__ wb) {
  const int NX4 = Bn * Sn * Hn / 4;
  const int NW4 = Hn * Hn / 4;
  const int total = NX4 + 3 * NW4;
  for (int i = blockIdx.x * 256 + threadIdx.x; i < total; i += gridDim.x * 256) {
    const fvec4* s; us4* d; int j;
    if (i < NX4)                { s = (const fvec4*)x;  d = (us4*)xb;             j = i; }
    else if (i < NX4 + NW4)     { s = (const fvec4*)wq; d = (us4*)wb;             j = i - NX4; }
    else if (i < NX4 + 2 * NW4) { s = (const fvec4*)wk; d = (us4*)(wb + Hn * Hn); j = i - NX4 - NW4; }
    else                        { s = (const fvec4*)wv; d = (us4*)(wb + 2 * Hn * Hn); j = i - NX4 - 2 * NW4; }
    fvec4 v = s[j];
    us4 o;
    o[0] = f2bf(v[0]); o[1] = f2bf(v[1]); o[2] = f2bf(v[2]); o[3] = f2bf(v[3]);
    d[j] = o;
  }
}

// ---------------- bf16 B^T GEMM, bf16 out, column-routed (Q|K) ----------------
// C[m,n] = sum_k A[m,k] * B[n,k];  cols >= n_split go to C1 (col - n_split)
__global__ __launch_bounds__(256) void gemm_bt_bf16_kernel(
    const unsigned short* __restrict__ A, int lda,
    const unsigned short* __restrict__ Bm, int ldb,
    unsigned short* __restrict__ C0, unsigned short* __restrict__ C1,
    int n_split, int ldc, int K) {
  __shared__ __attribute__((aligned(16))) unsigned short As[128 * 32];
  __shared__ __attribute__((aligned(16))) unsigned short Bs[128 * 32];
  const int tid = threadIdx.x, lane = tid & 63, wave = tid >> 6;
  const int wr = wave >> 1, wc = wave & 1;
  const int bm = blockIdx.x, bn = blockIdx.y;

  const unsigned short* Ag = A + (int64_t)(bm * 128 + wave * 32 + (lane >> 2)) * lda + (lane & 3) * 8;
  const unsigned short* Bg = Bm + (int64_t)(bn * 128 + wave * 32 + (lane >> 2)) * ldb + (lane & 3) * 8;
  char* AsW = (char*)As + wave * 2048;
  char* BsW = (char*)Bs + wave * 2048;

  f32x4 zero = {0.f, 0.f, 0.f, 0.f};
  f32x4 acc[4][4];
#pragma unroll
  for (int m = 0; m < 4; m++)
#pragma unroll
    for (int n = 0; n < 4; n++) acc[m][n] = zero;

  const int nkt = K >> 5;
  for (int kt = 0; kt < nkt; ++kt) {
    const int k0 = kt << 5;
    gload16((void*)(Ag + k0), AsW);
    gload16((void*)(Ag + k0 + 16 * lda), AsW + 1024);
    gload16((void*)(Bg + k0), BsW);
    gload16((void*)(Bg + k0 + 16 * ldb), BsW + 1024);
    __syncthreads();
    const short* Ap = (const short*)As;
    const short* Bp = (const short*)Bs;
    const int ko = (lane >> 4) * 8;
    short8 af[4], bfv[4];
#pragma unroll
    for (int m = 0; m < 4; m++)
      af[m] = *(const short8*)(Ap + (wr * 64 + m * 16 + (lane & 15)) * 32 + ko);
#pragma unroll
    for (int n = 0; n < 4; n++)
      bfv[n] = *(const short8*)(Bp + (wc * 64 + n * 16 + (lane & 15)) * 32 + ko);
#pragma unroll
    for (int m = 0; m < 4; m++)
#pragma unroll
      for (int n = 0; n < 4; n++)
        acc[m][n] = __builtin_amdgcn_mfma_f32_16x16x32_bf16(af[m], bfv[n], acc[m][n], 0, 0, 0);
    __syncthreads();
  }

#pragma unroll
  for (int n = 0; n < 4; n++) {
    int cc = bn * 128 + wc * 64 + n * 16;
    unsigned short* cb = C0;
    if (cc >= n_split) { cb = C1; cc -= n_split; }
    cc += (lane & 15);
#pragma unroll
    for (int m = 0; m < 4; m++) {
      const int r0 = bm * 128 + wr * 64 + m * 16 + ((lane >> 4) << 2);
#pragma unroll
      for (int j = 0; j < 4; j++)
        cb[(int64_t)(r0 + j) * ldc + cc] = f2bf(acc[m][n][j]);
    }
  }
}

// ---------------- scores = Q K^T * SCALE (fp32 out), causal tile skip ----------------
__global__ __launch_bounds__(256) void scores_kernel(
    const unsigned short* __restrict__ Qb, const unsigned short* __restrict__ Kbuf,
    float* __restrict__ Sc, int64_t sc_zstride, int b0) {
  const int bm = blockIdx.x, bn = blockIdx.y;
  if (bm < bn) return;  // fully masked tile
  const int b = b0 + blockIdx.z;
  const unsigned short* A = Qb + (int64_t)b * Sn * Hn;
  const unsigned short* Bm = Kbuf + (int64_t)b * Sn * Hn;
  float* C = Sc + (int64_t)blockIdx.z * sc_zstride;

  __shared__ __attribute__((aligned(16))) unsigned short As[128 * 32];
  __shared__ __attribute__((aligned(16))) unsigned short Bs[128 * 32];
  const int tid = threadIdx.x, lane = tid & 63, wave = tid >> 6;
  const int wr = wave >> 1, wc = wave & 1;

  const unsigned short* Ag = A + (int64_t)(bm * 128 + wave * 32 + (lane >> 2)) * Hn + (lane & 3) * 8;
  const unsigned short* Bg = Bm + (int64_t)(bn * 128 + wave * 32 + (lane >> 2)) * Hn + (lane & 3) * 8;
  char* AsW = (char*)As + wave * 2048;
  char* BsW = (char*)Bs + wave * 2048;

  f32x4 zero = {0.f, 0.f, 0.f, 0.f};
  f32x4 acc[4][4];
#pragma unroll
  for (int m = 0; m < 4; m++)
#pragma unroll
    for (int n = 0; n < 4; n++) acc[m][n] = zero;

  for (int kt = 0; kt < (Hn >> 5); ++kt) {
    const int k0 = kt << 5;
    gload16((void*)(Ag + k0), AsW);
    gload16((void*)(Ag + k0 + 16 * Hn), AsW + 1024);
    gload16((void*)(Bg + k0), BsW);
    gload16((void*)(Bg + k0 + 16 * Hn), BsW + 1024);
    __syncthreads();
    const short* Ap = (const short*)As;
    const short* Bp = (const short*)Bs;
    const int ko = (lane >> 4) * 8;
    short8 af[4], bfv[4];
#pragma unroll
    for (int m = 0; m < 4; m++)
      af[m] = *(const short8*)(Ap + (wr * 64 + m * 16 + (lane & 15)) * 32 + ko);
#pragma unroll
    for (int n = 0; n < 4; n++)
      bfv[n] = *(const short8*)(Bp + (wc * 64 + n * 16 + (lane & 15)) * 32 + ko);
#pragma unroll
    for (int m = 0; m < 4; m++)
#pragma unroll
      for (int n = 0; n < 4; n++)
        acc[m][n] = __builtin_amdgcn_mfma_f32_16x16x32_bf16(af[m], bfv[n], acc[m][n], 0, 0, 0);
    __syncthreads();
  }

#pragma unroll
  for (int n = 0; n < 4; n++) {
    const int cc = bn * 128 + wc * 64 + n * 16 + (lane & 15);
#pragma unroll
    for (int m = 0; m < 4; m++) {
      const int r0 = bm * 128 + wr * 64 + m * 16 + ((lane >> 4) << 2);
#pragma unroll
      for (int j = 0; j < 4; j++)
        C[(int64_t)(r0 + j) * Sn + cc] = acc[m][n][j] * SCALE_F;
    }
  }
}

// ---------------- O = softmax(S) V, fused: P=exp(S) staged to LDS, l accumulated ----------------
__global__ __launch_bounds__(256) void pv_kernel(
    const float* __restrict__ Sc, int64_t sc_zstride,
    const unsigned short* __restrict__ VTb,  // [Hn][Bn*Sn]
    float* __restrict__ Out, int b0) {
  __shared__ __attribute__((aligned(16))) short Ps[128 * 40];  // padded pitch 40
  __shared__ __attribute__((aligned(16))) unsigned short Vs[128 * 32];
  __shared__ float l_lds[128];
  const int tid = threadIdx.x, lane = tid & 63, wave = tid >> 6;
  const int wr = wave >> 1, wc = wave & 1;
  const int bq = blockIdx.x, bn = blockIdx.y;
  const int b = b0 + blockIdx.z;
  const float* Sb = Sc + (int64_t)blockIdx.z * sc_zstride;

  const int r = tid >> 1;           // staging row (0..127)
  const int kc = (tid & 1) * 16;    // staging col chunk
  const int qg = bq * 128 + r;

  const unsigned short* Vg = VTb + (int64_t)(bn * 128 + wave * 32 + (lane >> 2)) * (Bn * Sn)
                             + (int64_t)b * Sn + (lane & 3) * 8;
  char* VsW = (char*)Vs + wave * 2048;

  f32x4 zero = {0.f, 0.f, 0.f, 0.f};
  f32x4 acc[4][4];
#pragma unroll
  for (int m = 0; m < 4; m++)
#pragma unroll
    for (int n = 0; n < 4; n++) acc[m][n] = zero;

  float l_acc = 0.f;
  const int nkt = bq * 4 + 4;  // covers k < (bq+1)*128
  for (int kt = 0; kt < nkt; ++kt) {
    const int k0 = kt << 5;
    // ---- stage P tile: load fp32 scores, mask+exp, bf16, ds_write ----
    const fvec4* sp4 = (const fvec4*)(Sb + (int64_t)qg * Sn + k0 + kc);
    float lsum = 0.f;
    short8 plo, phi;
#pragma unroll
    for (int v4 = 0; v4 < 4; ++v4) {
      fvec4 sv = sp4[v4];
#pragma unroll
      for (int e = 0; e < 4; ++e) {
        const int k = k0 + kc + v4 * 4 + e;
        const float p = (k <= qg) ? __builtin_amdgcn_exp2f(sv[e] * LOG2E_F) : 0.f;
        lsum += p;
        const short pb = (short)f2bf(p);
        if (v4 < 2) plo[v4 * 4 + e] = pb; else phi[(v4 - 2) * 4 + e] = pb;
      }
    }
    *(short8*)(Ps + r * 40 + kc) = plo;
    *(short8*)(Ps + r * 40 + kc + 8) = phi;
    l_acc += lsum + __shfl_xor(lsum, 1);
    // ---- stage V tile ----
    gload16((void*)(Vg + k0), VsW);
    gload16((void*)(Vg + k0 + (int64_t)16 * (Bn * Sn)), VsW + 1024);
    __syncthreads();
    // ---- fragments + MFMA ----
    const short* Pp = (const short*)Ps;
    const short* Vp = (const short*)Vs;
    const int ko = (lane >> 4) * 8;
    short8 af[4], bfv[4];
#pragma unroll
    for (int m = 0; m < 4; m++)
      af[m] = *(const short8*)(Pp + (wr * 64 + m * 16 + (lane & 15)) * 40 + ko);
#pragma unroll
    for (int n = 0; n < 4; n++)
      bfv[n] = *(const short8*)(Vp + (wc * 64 + n * 16 + (lane & 15)) * 32 + ko);
#pragma unroll
    for (int m = 0; m < 4; m++)
#pragma unroll
      for (int n = 0; n < 4; n++)
        acc[m][n] = __builtin_amdgcn_mfma_f32_16x16x32_bf16(af[m], bfv[n], acc[m][n], 0, 0, 0);
    __syncthreads();
  }

  if ((tid & 1) == 0) l_lds[r] = l_acc;
  __syncthreads();

#pragma unroll
  for (int m = 0; m < 4; m++) {
    const int r0 = wr * 64 + m * 16 + ((lane >> 4) << 2);
#pragma unroll
    for (int j = 0; j < 4; j++) {
      const float linv = 1.0f / l_lds[r0 + j];
      const int q = bq * 128 + r0 + j;
#pragma unroll
      for (int n = 0; n < 4; n++) {
        const int d = bn * 128 + wc * 64 + n * 16 + (lane & 15);
        Out[(int64_t)b * Sn * Hn + (int64_t)q * Hn + d] = acc[m][n][j] * linv;
      }
    }
  }
}

// ---------------- host launch ----------------
extern "C" void kernel_launch(void* const* d_in, const int* in_sizes, int n_in,
                              void* d_out, int out_size, void* d_ws, size_t ws_size,
                              hipStream_t stream) {
  const float* x  = (const float*)d_in[0];
  // d_in[1] = attention_mask (causal tril by construction) — not needed
  const float* wq = (const float*)d_in[2];
  const float* wk = (const float*)d_in[3];
  const float* wv = (const float*)d_in[4];
  float* out = (float*)d_out;
  char* ws = (char*)d_ws;

  unsigned short* xb = (unsigned short*)(ws);                 // 16 MB
  unsigned short* wb = (unsigned short*)(ws + (16ll << 20));  // 6 MB (wq|wk|wv)
  unsigned short* Qb = (unsigned short*)(ws + (22ll << 20));  // 16 MB
  unsigned short* Kb = (unsigned short*)(ws + (38ll << 20));  // 16 MB
  unsigned short* VT = (unsigned short*)(ws + (54ll << 20));  // 16 MB  [Hn][Bn*Sn]
  float* Sc          = (float*)(ws + (70ll << 20));           // 64 MB (or 16 MB per-batch)

  // 1. fp32 -> bf16
  cvt_kernel<<<2048, 256, 0, stream>>>(x, wq, wk, wv, xb, wb);
  // 2. Q,K projection: M=8192, N=2048 (wq|wk), K=1024, routed outputs
  gemm_bt_bf16_kernel<<<dim3(64, 16), 256, 0, stream>>>(
      xb, 1024, wb, 1024, Qb, Kb, 1024, 1024, 1024);
  // 3. V^T = Wv * x^T: M=1024 (d), N=8192 (b,s), K=1024
  gemm_bt_bf16_kernel<<<dim3(8, 64), 256, 0, stream>>>(
      wb + 2 * 1024 * 1024, 1024, xb, 1024, VT, VT, 1 << 30, 8192, 1024);

  if (ws_size >= (134ull << 20)) {
    scores_kernel<<<dim3(16, 16, 4), 256, 0, stream>>>(Qb, Kb, Sc, (int64_t)Sn * Sn, 0);
    pv_kernel<<<dim3(16, 8, 4), 256, 0, stream>>>(Sc, (int64_t)Sn * Sn, VT, out, 0);
  } else {
    // scratch too small for all batches: reuse one 16 MB scores buffer per batch
    for (int b = 0; b < 4; ++b) {
      scores_kernel<<<dim3(16, 16, 1), 256, 0, stream>>>(Qb, Kb, Sc, 0, b);
      pv_kernel<<<dim3(16, 8, 1), 256, 0, stream>>>(Sc, 0, VT, out, b);
    }
  }
}

// Round 3
// 201.412 us; speedup vs baseline: 1.1547x; 1.1547x over previous
//
#include <hip/hip_runtime.h>
#include <hip/hip_bf16.h>
#include <stdint.h>

typedef __attribute__((ext_vector_type(8))) short short8;
typedef __attribute__((ext_vector_type(4))) float f32x4;
typedef __attribute__((ext_vector_type(4))) float fvec4;
typedef __attribute__((ext_vector_type(4))) unsigned short us4;

#define DEV static __device__ __forceinline__

constexpr int Hn = 1024;
constexpr int Bn = 4;
constexpr int Sn = 2048;
constexpr float SCALE_F = 0.03125f;           // 1/sqrt(1024)
constexpr float LOG2E_F = 1.4426950408889634f;
constexpr float CEXP = SCALE_F * LOG2E_F;     // exp(s*SCALE) = exp2(s*CEXP)

DEV unsigned short f2bf(float f) {
  union { float f; unsigned u; } c; c.f = f;
  unsigned r = c.u + 0x7fffu + ((c.u >> 16) & 1u);   // RNE
  return (unsigned short)(r >> 16);
}

DEV float bf2f(unsigned short b) {
  union { unsigned u; float f; } c; c.u = ((unsigned)b) << 16;
  return c.f;
}

DEV void gload16(void* g, void* l) {
  __builtin_amdgcn_global_load_lds(
      (__attribute__((address_space(1))) void*)g,
      (__attribute__((address_space(3))) void*)l, 16, 0, 0);
}

// ---------------- fp32 -> bf16 convert (x, wq, wk, wv) ----------------
__global__ __launch_bounds__(256) void cvt_kernel(
    const float* __restrict__ x, const float* __restrict__ wq,
    const float* __restrict__ wk, const float* __restrict__ wv,
    unsigned short* __restrict__ xb, unsigned short* __restrict__ wb) {
  const int NX4 = Bn * Sn * Hn / 4;
  const int NW4 = Hn * Hn / 4;
  const int total = NX4 + 3 * NW4;
  for (int i = blockIdx.x * 256 + threadIdx.x; i < total; i += gridDim.x * 256) {
    const fvec4* s; us4* d; int j;
    if (i < NX4)                { s = (const fvec4*)x;  d = (us4*)xb;             j = i; }
    else if (i < NX4 + NW4)     { s = (const fvec4*)wq; d = (us4*)wb;             j = i - NX4; }
    else if (i < NX4 + 2 * NW4) { s = (const fvec4*)wk; d = (us4*)(wb + Hn * Hn); j = i - NX4 - NW4; }
    else                        { s = (const fvec4*)wv; d = (us4*)(wb + 2 * Hn * Hn); j = i - NX4 - 2 * NW4; }
    fvec4 v = s[j];
    us4 o;
    o[0] = f2bf(v[0]); o[1] = f2bf(v[1]); o[2] = f2bf(v[2]); o[3] = f2bf(v[3]);
    d[j] = o;
  }
}

// ---------------- bf16 B^T GEMM, bf16 out, column-routed (Q|K) ----------------
// C[m,n] = sum_k A[m,k] * B[n,k];  cols >= n_split go to C1 (col - n_split)
__global__ __launch_bounds__(256) void gemm_bt_bf16_kernel(
    const unsigned short* __restrict__ A, int lda,
    const unsigned short* __restrict__ Bm, int ldb,
    unsigned short* __restrict__ C0, unsigned short* __restrict__ C1,
    int n_split, int ldc, int K) {
  __shared__ __attribute__((aligned(16))) unsigned short As[128 * 32];
  __shared__ __attribute__((aligned(16))) unsigned short Bs[128 * 32];
  const int tid = threadIdx.x, lane = tid & 63, wave = tid >> 6;
  const int wr = wave >> 1, wc = wave & 1;
  const int bm = blockIdx.x, bn = blockIdx.y;

  const unsigned short* Ag = A + (int64_t)(bm * 128 + wave * 32 + (lane >> 2)) * lda + (lane & 3) * 8;
  const unsigned short* Bg = Bm + (int64_t)(bn * 128 + wave * 32 + (lane >> 2)) * ldb + (lane & 3) * 8;
  char* AsW = (char*)As + wave * 2048;
  char* BsW = (char*)Bs + wave * 2048;

  f32x4 zero = {0.f, 0.f, 0.f, 0.f};
  f32x4 acc[4][4];
#pragma unroll
  for (int m = 0; m < 4; m++)
#pragma unroll
    for (int n = 0; n < 4; n++) acc[m][n] = zero;

  const int nkt = K >> 5;
  for (int kt = 0; kt < nkt; ++kt) {
    const int k0 = kt << 5;
    gload16((void*)(Ag + k0), AsW);
    gload16((void*)(Ag + k0 + 16 * lda), AsW + 1024);
    gload16((void*)(Bg + k0), BsW);
    gload16((void*)(Bg + k0 + 16 * ldb), BsW + 1024);
    __syncthreads();
    const short* Ap = (const short*)As;
    const short* Bp = (const short*)Bs;
    const int ko = (lane >> 4) * 8;
    short8 af[4], bfv[4];
#pragma unroll
    for (int m = 0; m < 4; m++)
      af[m] = *(const short8*)(Ap + (wr * 64 + m * 16 + (lane & 15)) * 32 + ko);
#pragma unroll
    for (int n = 0; n < 4; n++)
      bfv[n] = *(const short8*)(Bp + (wc * 64 + n * 16 + (lane & 15)) * 32 + ko);
#pragma unroll
    for (int m = 0; m < 4; m++)
#pragma unroll
      for (int n = 0; n < 4; n++)
        acc[m][n] = __builtin_amdgcn_mfma_f32_16x16x32_bf16(af[m], bfv[n], acc[m][n], 0, 0, 0);
    __syncthreads();
  }

#pragma unroll
  for (int n = 0; n < 4; n++) {
    int cc = bn * 128 + wc * 64 + n * 16;
    unsigned short* cb = C0;
    if (cc >= n_split) { cb = C1; cc -= n_split; }
    cc += (lane & 15);
#pragma unroll
    for (int m = 0; m < 4; m++) {
      const int r0 = bm * 128 + wr * 64 + m * 16 + ((lane >> 4) << 2);
#pragma unroll
      for (int j = 0; j < 4; j++)
        cb[(int64_t)(r0 + j) * ldc + cc] = f2bf(acc[m][n][j]);
    }
  }
}

// ---------------- P = exp(Q K^T * SCALE) masked, bf16 out; causal tile skip ----------------
__global__ __launch_bounds__(256) void scores_exp_kernel(
    const unsigned short* __restrict__ Qb, const unsigned short* __restrict__ Kbuf,
    unsigned short* __restrict__ P, int64_t p_zstride, int b0) {
  const int bm = blockIdx.x, bn = blockIdx.y;
  if (bm < bn) return;  // fully masked tile
  const int b = b0 + blockIdx.z;
  const unsigned short* A = Qb + (int64_t)b * Sn * Hn;
  const unsigned short* Bm = Kbuf + (int64_t)b * Sn * Hn;
  unsigned short* C = P + (int64_t)blockIdx.z * p_zstride;

  __shared__ __attribute__((aligned(16))) unsigned short As[128 * 32];
  __shared__ __attribute__((aligned(16))) unsigned short Bs[128 * 32];
  const int tid = threadIdx.x, lane = tid & 63, wave = tid >> 6;
  const int wr = wave >> 1, wc = wave & 1;

  const unsigned short* Ag = A + (int64_t)(bm * 128 + wave * 32 + (lane >> 2)) * Hn + (lane & 3) * 8;
  const unsigned short* Bg = Bm + (int64_t)(bn * 128 + wave * 32 + (lane >> 2)) * Hn + (lane & 3) * 8;
  char* AsW = (char*)As + wave * 2048;
  char* BsW = (char*)Bs + wave * 2048;

  f32x4 zero = {0.f, 0.f, 0.f, 0.f};
  f32x4 acc[4][4];
#pragma unroll
  for (int m = 0; m < 4; m++)
#pragma unroll
    for (int n = 0; n < 4; n++) acc[m][n] = zero;

  for (int kt = 0; kt < (Hn >> 5); ++kt) {
    const int k0 = kt << 5;
    gload16((void*)(Ag + k0), AsW);
    gload16((void*)(Ag + k0 + 16 * Hn), AsW + 1024);
    gload16((void*)(Bg + k0), BsW);
    gload16((void*)(Bg + k0 + 16 * Hn), BsW + 1024);
    __syncthreads();
    const short* Ap = (const short*)As;
    const short* Bp = (const short*)Bs;
    const int ko = (lane >> 4) * 8;
    short8 af[4], bfv[4];
#pragma unroll
    for (int m = 0; m < 4; m++)
      af[m] = *(const short8*)(Ap + (wr * 64 + m * 16 + (lane & 15)) * 32 + ko);
#pragma unroll
    for (int n = 0; n < 4; n++)
      bfv[n] = *(const short8*)(Bp + (wc * 64 + n * 16 + (lane & 15)) * 32 + ko);
#pragma unroll
    for (int m = 0; m < 4; m++)
#pragma unroll
      for (int n = 0; n < 4; n++)
        acc[m][n] = __builtin_amdgcn_mfma_f32_16x16x32_bf16(af[m], bfv[n], acc[m][n], 0, 0, 0);
    __syncthreads();
  }

  // epilogue: mask + exp2 + bf16
#pragma unroll
  for (int n = 0; n < 4; n++) {
    const int cc = bn * 128 + wc * 64 + n * 16 + (lane & 15);
#pragma unroll
    for (int m = 0; m < 4; m++) {
      const int r0 = bm * 128 + wr * 64 + m * 16 + ((lane >> 4) << 2);
#pragma unroll
      for (int j = 0; j < 4; j++) {
        const int row = r0 + j;
        const float p = (cc <= row) ? __builtin_amdgcn_exp2f(acc[m][n][j] * CEXP) : 0.f;
        C[(int64_t)row * Sn + cc] = f2bf(p);
      }
    }
  }
}

// ---------------- l[row] = sum_{k<=q} P[row][k]  (one row per wave) ----------------
__global__ __launch_bounds__(256) void rowsum_kernel(
    const unsigned short* __restrict__ P, float* __restrict__ l, int b0, int nb) {
  const int lane = threadIdx.x & 63, wave = threadIdx.x >> 6;
  const int r = blockIdx.x * 4 + wave;          // local row id over nb batches
  if (r >= nb * Sn) return;
  const int bl = r >> 11;                       // local batch
  const int q = r & (Sn - 1);
  const unsigned short* Pr = P + (int64_t)bl * Sn * Sn + (int64_t)q * Sn;
  float s = 0.f;
  for (int base = lane * 8; base < Sn; base += 512) {
    const int rem = q + 1 - base;
    if (rem <= 0) continue;
    short8 v = *(const short8*)(Pr + base);
#pragma unroll
    for (int e = 0; e < 8; ++e)
      if (e < rem) s += bf2f((unsigned short)v[e]);
  }
#pragma unroll
  for (int m = 1; m < 64; m <<= 1) s += __shfl_xor(s, m);
  if (lane == 0) l[(int64_t)(b0 + bl) * Sn + q] = s;
}

// ---------------- O = (P V) / l : B^T GEMM with causal K bound + 1/l epilogue ----------------
__global__ __launch_bounds__(256) void pv_gemm_kernel(
    const unsigned short* __restrict__ P, int64_t p_zstride,
    const unsigned short* __restrict__ VTb,  // [Hn][Bn*Sn]
    const float* __restrict__ l,
    float* __restrict__ Out, int b0) {
  __shared__ __attribute__((aligned(16))) unsigned short As[128 * 32];
  __shared__ __attribute__((aligned(16))) unsigned short Bs[128 * 32];
  const int tid = threadIdx.x, lane = tid & 63, wave = tid >> 6;
  const int wr = wave >> 1, wc = wave & 1;
  const int bm = blockIdx.x, bn = blockIdx.y;
  const int b = b0 + blockIdx.z;

  const unsigned short* A = P + (int64_t)blockIdx.z * p_zstride;
  const unsigned short* Ag = A + (int64_t)(bm * 128 + wave * 32 + (lane >> 2)) * Sn + (lane & 3) * 8;
  const unsigned short* Bg = VTb + (int64_t)(bn * 128 + wave * 32 + (lane >> 2)) * (Bn * Sn)
                             + (int64_t)b * Sn + (lane & 3) * 8;
  char* AsW = (char*)As + wave * 2048;
  char* BsW = (char*)Bs + wave * 2048;

  f32x4 zero = {0.f, 0.f, 0.f, 0.f};
  f32x4 acc[4][4];
#pragma unroll
  for (int m = 0; m < 4; m++)
#pragma unroll
    for (int n = 0; n < 4; n++) acc[m][n] = zero;

  const int nkt = (bm + 1) * 4;  // causal: k < (bm+1)*128
  for (int kt = 0; kt < nkt; ++kt) {
    const int k0 = kt << 5;
    gload16((void*)(Ag + k0), AsW);
    gload16((void*)(Ag + k0 + 16 * Sn), AsW + 1024);
    gload16((void*)(Bg + k0), BsW);
    gload16((void*)(Bg + k0 + (int64_t)16 * (Bn * Sn)), BsW + 1024);
    __syncthreads();
    const short* Ap = (const short*)As;
    const short* Bp = (const short*)Bs;
    const int ko = (lane >> 4) * 8;
    short8 af[4], bfv[4];
#pragma unroll
    for (int m = 0; m < 4; m++)
      af[m] = *(const short8*)(Ap + (wr * 64 + m * 16 + (lane & 15)) * 32 + ko);
#pragma unroll
    for (int n = 0; n < 4; n++)
      bfv[n] = *(const short8*)(Bp + (wc * 64 + n * 16 + (lane & 15)) * 32 + ko);
#pragma unroll
    for (int m = 0; m < 4; m++)
#pragma unroll
      for (int n = 0; n < 4; n++)
        acc[m][n] = __builtin_amdgcn_mfma_f32_16x16x32_bf16(af[m], bfv[n], acc[m][n], 0, 0, 0);
    __syncthreads();
  }

#pragma unroll
  for (int m = 0; m < 4; m++) {
    const int r0 = bm * 128 + wr * 64 + m * 16 + ((lane >> 4) << 2);
#pragma unroll
    for (int j = 0; j < 4; j++) {
      const int q = r0 + j;
      const float linv = 1.0f / l[(int64_t)b * Sn + q];
#pragma unroll
      for (int n = 0; n < 4; n++) {
        const int d = bn * 128 + wc * 64 + n * 16 + (lane & 15);
        Out[(int64_t)b * Sn * Hn + (int64_t)q * Hn + d] = acc[m][n][j] * linv;
      }
    }
  }
}

// ---------------- host launch ----------------
extern "C" void kernel_launch(void* const* d_in, const int* in_sizes, int n_in,
                              void* d_out, int out_size, void* d_ws, size_t ws_size,
                              hipStream_t stream) {
  const float* x  = (const float*)d_in[0];
  // d_in[1] = attention_mask (causal tril by construction) — not needed
  const float* wq = (const float*)d_in[2];
  const float* wk = (const float*)d_in[3];
  const float* wv = (const float*)d_in[4];
  float* out = (float*)d_out;
  char* ws = (char*)d_ws;

  const int64_t MiB = 1ll << 20;
  unsigned short* xb = (unsigned short*)(ws);              // 16 MiB
  unsigned short* wb = (unsigned short*)(ws + 16 * MiB);   // 6 MiB (wq|wk|wv)
  float* l           = (float*)(ws + 22 * MiB);            // 32 KiB
  unsigned short* Qb = (unsigned short*)(ws + 23 * MiB);   // 16 MiB
  unsigned short* Kb = (unsigned short*)(ws + 39 * MiB);   // 16 MiB
  unsigned short* VT = (unsigned short*)(ws + 55 * MiB);   // 16 MiB  [Hn][Bn*Sn]
  unsigned short* P  = (unsigned short*)(ws + 71 * MiB);   // up to 32 MiB (bf16 [nb][S][S])

  // 1. fp32 -> bf16
  cvt_kernel<<<2048, 256, 0, stream>>>(x, wq, wk, wv, xb, wb);
  // 2. Q,K projection: M=8192, N=2048 (wq|wk), K=1024, routed outputs
  gemm_bt_bf16_kernel<<<dim3(64, 16), 256, 0, stream>>>(
      xb, 1024, wb, 1024, Qb, Kb, 1024, 1024, 1024);
  // 3. V^T = Wv * x^T: M=1024 (d), N=8192 (b,s), K=1024
  gemm_bt_bf16_kernel<<<dim3(8, 64), 256, 0, stream>>>(
      wb + 2 * 1024 * 1024, 1024, xb, 1024, VT, VT, 1 << 30, 8192, 1024);

  // 4-6. per-batch-group: P = exp(QK^T*scale), l = rowsum(P), O = (P V)/l
  int nb = 1;
  if (ws_size >= 103ull * MiB) nb = 4;
  else if (ws_size >= 87ull * MiB) nb = 2;
  for (int b0 = 0; b0 < Bn; b0 += nb) {
    scores_exp_kernel<<<dim3(16, 16, nb), 256, 0, stream>>>(
        Qb, Kb, P, (int64_t)Sn * Sn, b0);
    rowsum_kernel<<<nb * 512, 256, 0, stream>>>(P, l, b0, nb);
    pv_gemm_kernel<<<dim3(16, 8, nb), 256, 0, stream>>>(
        P, (int64_t)Sn * Sn, VT, l, out, b0);
  }
}

// Round 4
// 179.607 us; speedup vs baseline: 1.2949x; 1.1214x over previous
//
#include <hip/hip_runtime.h>
#include <hip/hip_bf16.h>
#include <stdint.h>

typedef __attribute__((ext_vector_type(8))) short short8;
typedef __attribute__((ext_vector_type(4))) float f32x4;
typedef __attribute__((ext_vector_type(4))) float fvec4;
typedef __attribute__((ext_vector_type(4))) unsigned short us4;

#define DEV static __device__ __forceinline__

constexpr int Hn = 1024;
constexpr int Bn = 4;
constexpr int Sn = 2048;
constexpr float SCALE_F = 0.03125f;           // 1/sqrt(1024)
constexpr float LOG2E_F = 1.4426950408889634f;
constexpr float CEXP = SCALE_F * LOG2E_F;     // exp(s*SCALE) = exp2(s*CEXP)

DEV unsigned short f2bf(float f) {
  union { float f; unsigned u; } c; c.f = f;
  unsigned r = c.u + 0x7fffu + ((c.u >> 16) & 1u);   // RNE
  return (unsigned short)(r >> 16);
}

DEV float bf2f(unsigned short b) {
  union { unsigned u; float f; } c; c.u = ((unsigned)b) << 16;
  return c.f;
}

DEV void gload16(const void* g, void* l) {
  __builtin_amdgcn_global_load_lds(
      (const __attribute__((address_space(1))) void*)g,
      (__attribute__((address_space(3))) void*)l, 16, 0, 0);
}

// ---------------- fp32 -> bf16 convert (x, wq, wk, wv) ----------------
__global__ __launch_bounds__(256) void cvt_kernel(
    const float* __restrict__ x, const float* __restrict__ wq,
    const float* __restrict__ wk, const float* __restrict__ wv,
    unsigned short* __restrict__ xb, unsigned short* __restrict__ wb) {
  const int NX4 = Bn * Sn * Hn / 4;
  const int NW4 = Hn * Hn / 4;
  const int total = NX4 + 3 * NW4;
  for (int i = blockIdx.x * 256 + threadIdx.x; i < total; i += gridDim.x * 256) {
    const fvec4* s; us4* d; int j;
    if (i < NX4)                { s = (const fvec4*)x;  d = (us4*)xb;             j = i; }
    else if (i < NX4 + NW4)     { s = (const fvec4*)wq; d = (us4*)wb;             j = i - NX4; }
    else if (i < NX4 + 2 * NW4) { s = (const fvec4*)wk; d = (us4*)(wb + Hn * Hn); j = i - NX4 - NW4; }
    else                        { s = (const fvec4*)wv; d = (us4*)(wb + 2 * Hn * Hn); j = i - NX4 - 2 * NW4; }
    fvec4 v = s[j];
    us4 o;
    o[0] = f2bf(v[0]); o[1] = f2bf(v[1]); o[2] = f2bf(v[2]); o[3] = f2bf(v[3]);
    d[j] = o;
  }
}

// ---------------- generic bf16 B^T GEMM, double-buffered (2-phase), routed bf16 out ----
// grid flattened 1D with m204 XCD swizzle; bm = wgid & bm_mask, bn = wgid >> bm_shift
__global__ __launch_bounds__(256) void gemm_bt_dbuf_kernel(
    const unsigned short* __restrict__ A, int lda,
    const unsigned short* __restrict__ Bm, int ldb,
    unsigned short* __restrict__ C0, unsigned short* __restrict__ C1,
    int n_split, int ldc, int bm_mask, int bm_shift, int K) {
  __shared__ __attribute__((aligned(16))) unsigned short As[2][128 * 32];
  __shared__ __attribute__((aligned(16))) unsigned short Bs[2][128 * 32];
  const int tid = threadIdx.x, lane = tid & 63, wave = tid >> 6;
  const int wr = wave >> 1, wc = wave & 1;
  // bijective XCD swizzle (gridDim.x % 8 == 0)
  const int q8 = gridDim.x >> 3;
  const int wgid = (blockIdx.x & 7) * q8 + (blockIdx.x >> 3);
  const int bm = wgid & bm_mask, bn = wgid >> bm_shift;

  const unsigned short* Ag = A + (int64_t)(bm * 128 + wave * 32 + (lane >> 2)) * lda + (lane & 3) * 8;
  const unsigned short* Bg = Bm + (int64_t)(bn * 128 + wave * 32 + (lane >> 2)) * ldb + (lane & 3) * 8;

  f32x4 zero = {0.f, 0.f, 0.f, 0.f};
  f32x4 acc[4][4];
#pragma unroll
  for (int m = 0; m < 4; m++)
#pragma unroll
    for (int n = 0; n < 4; n++) acc[m][n] = zero;

  auto stage = [&](int kt, int buf) {
    const int k0 = kt << 5;
    char* a = (char*)As[buf] + wave * 2048;
    char* b = (char*)Bs[buf] + wave * 2048;
    gload16(Ag + k0, a);
    gload16(Ag + k0 + 16 * lda, a + 1024);
    gload16(Bg + k0, b);
    gload16(Bg + k0 + 16 * ldb, b + 1024);
  };

  const int nkt = K >> 5;
  stage(0, 0);
  __syncthreads();
  for (int kt = 0; kt < nkt; ++kt) {
    const int buf = kt & 1;
    if (kt + 1 < nkt) stage(kt + 1, buf ^ 1);  // prefetch overlaps MFMA below
    const short* Ap = (const short*)As[buf];
    const short* Bp = (const short*)Bs[buf];
    const int ko = (lane >> 4) * 8;
    short8 af[4], bfv[4];
#pragma unroll
    for (int m = 0; m < 4; m++)
      af[m] = *(const short8*)(Ap + (wr * 64 + m * 16 + (lane & 15)) * 32 + ko);
#pragma unroll
    for (int n = 0; n < 4; n++)
      bfv[n] = *(const short8*)(Bp + (wc * 64 + n * 16 + (lane & 15)) * 32 + ko);
#pragma unroll
    for (int m = 0; m < 4; m++)
#pragma unroll
      for (int n = 0; n < 4; n++)
        acc[m][n] = __builtin_amdgcn_mfma_f32_16x16x32_bf16(af[m], bfv[n], acc[m][n], 0, 0, 0);
    __syncthreads();  // drains prefetch (vmcnt 0) + all waves past ds_reads of buf
  }

#pragma unroll
  for (int n = 0; n < 4; n++) {
    int cc = bn * 128 + wc * 64 + n * 16;
    unsigned short* cb = C0;
    if (cc >= n_split) { cb = C1; cc -= n_split; }
    cc += (lane & 15);
#pragma unroll
    for (int m = 0; m < 4; m++) {
      const int r0 = bm * 128 + wr * 64 + m * 16 + ((lane >> 4) << 2);
#pragma unroll
      for (int j = 0; j < 4; j++)
        cb[(int64_t)(r0 + j) * ldc + cc] = f2bf(acc[m][n][j]);
    }
  }
}

// ---------------- P = exp(Q K^T * SCALE) masked, bf16 out; active tiles only ----------
__global__ __launch_bounds__(256) void scores_exp_kernel(
    const unsigned short* __restrict__ Qb, const unsigned short* __restrict__ Kbuf,
    unsigned short* __restrict__ P, int64_t p_zstride, int b0) {
  // flattened active causal tiles: per z, 136 tiles (bm >= bn)
  const int q8 = gridDim.x >> 3;
  const int wgid = (blockIdx.x & 7) * q8 + (blockIdx.x >> 3);
  const int zl = wgid / 136;
  const int t = wgid - zl * 136;
  int bm = (int)((sqrtf(8.f * t + 1.f) - 1.f) * 0.5f);
  if (bm * (bm + 1) / 2 > t) bm--;
  if ((bm + 1) * (bm + 2) / 2 <= t) bm++;
  const int bn = t - bm * (bm + 1) / 2;

  const int b = b0 + zl;
  const unsigned short* A = Qb + (int64_t)b * Sn * Hn;
  const unsigned short* Bm = Kbuf + (int64_t)b * Sn * Hn;
  unsigned short* C = P + (int64_t)zl * p_zstride;

  __shared__ __attribute__((aligned(16))) unsigned short As[2][128 * 32];
  __shared__ __attribute__((aligned(16))) unsigned short Bs[2][128 * 32];
  const int tid = threadIdx.x, lane = tid & 63, wave = tid >> 6;
  const int wr = wave >> 1, wc = wave & 1;

  const unsigned short* Ag = A + (int64_t)(bm * 128 + wave * 32 + (lane >> 2)) * Hn + (lane & 3) * 8;
  const unsigned short* Bg = Bm + (int64_t)(bn * 128 + wave * 32 + (lane >> 2)) * Hn + (lane & 3) * 8;

  f32x4 zero = {0.f, 0.f, 0.f, 0.f};
  f32x4 acc[4][4];
#pragma unroll
  for (int m = 0; m < 4; m++)
#pragma unroll
    for (int n = 0; n < 4; n++) acc[m][n] = zero;

  auto stage = [&](int kt, int buf) {
    const int k0 = kt << 5;
    char* a = (char*)As[buf] + wave * 2048;
    char* b2 = (char*)Bs[buf] + wave * 2048;
    gload16(Ag + k0, a);
    gload16(Ag + k0 + 16 * Hn, a + 1024);
    gload16(Bg + k0, b2);
    gload16(Bg + k0 + 16 * Hn, b2 + 1024);
  };

  stage(0, 0);
  __syncthreads();
  for (int kt = 0; kt < (Hn >> 5); ++kt) {
    const int buf = kt & 1;
    if (kt + 1 < (Hn >> 5)) stage(kt + 1, buf ^ 1);
    const short* Ap = (const short*)As[buf];
    const short* Bp = (const short*)Bs[buf];
    const int ko = (lane >> 4) * 8;
    short8 af[4], bfv[4];
#pragma unroll
    for (int m = 0; m < 4; m++)
      af[m] = *(const short8*)(Ap + (wr * 64 + m * 16 + (lane & 15)) * 32 + ko);
#pragma unroll
    for (int n = 0; n < 4; n++)
      bfv[n] = *(const short8*)(Bp + (wc * 64 + n * 16 + (lane & 15)) * 32 + ko);
#pragma unroll
    for (int m = 0; m < 4; m++)
#pragma unroll
      for (int n = 0; n < 4; n++)
        acc[m][n] = __builtin_amdgcn_mfma_f32_16x16x32_bf16(af[m], bfv[n], acc[m][n], 0, 0, 0);
    __syncthreads();
  }

  // epilogue: mask + exp2 + bf16
#pragma unroll
  for (int n = 0; n < 4; n++) {
    const int cc = bn * 128 + wc * 64 + n * 16 + (lane & 15);
#pragma unroll
    for (int m = 0; m < 4; m++) {
      const int r0 = bm * 128 + wr * 64 + m * 16 + ((lane >> 4) << 2);
#pragma unroll
      for (int j = 0; j < 4; j++) {
        const int row = r0 + j;
        const float p = (cc <= row) ? __builtin_amdgcn_exp2f(acc[m][n][j] * CEXP) : 0.f;
        C[(int64_t)row * Sn + cc] = f2bf(p);
      }
    }
  }
}

// ---------------- l[row] = sum_{k<=q} P[row][k]  (one row per wave) ----------------
__global__ __launch_bounds__(256) void rowsum_kernel(
    const unsigned short* __restrict__ P, float* __restrict__ l, int b0, int nb) {
  const int lane = threadIdx.x & 63, wave = threadIdx.x >> 6;
  const int r = blockIdx.x * 4 + wave;          // local row id over nb batches
  if (r >= nb * Sn) return;
  const int bl = r >> 11;                       // local batch
  const int q = r & (Sn - 1);
  const unsigned short* Pr = P + (int64_t)bl * Sn * Sn + (int64_t)q * Sn;
  float s = 0.f;
  for (int base = lane * 8; base < Sn; base += 512) {
    const int rem = q + 1 - base;
    if (rem <= 0) continue;
    short8 v = *(const short8*)(Pr + base);
#pragma unroll
    for (int e = 0; e < 8; ++e)
      if (e < rem) s += bf2f((unsigned short)v[e]);
  }
#pragma unroll
  for (int m = 1; m < 64; m <<= 1) s += __shfl_xor(s, m);
  if (lane == 0) l[(int64_t)(b0 + bl) * Sn + q] = s;
}

// ---------------- O = (P V) / l : dbuf B^T GEMM, causal K bound, heavy-first grid ----
__global__ __launch_bounds__(256) void pv_gemm_kernel(
    const unsigned short* __restrict__ P, int64_t p_zstride,
    const unsigned short* __restrict__ VTb,  // [Hn][Bn*Sn]
    const float* __restrict__ l,
    float* __restrict__ Out, int b0, int nb) {
  // heavy-first flatten: blocks with largest causal K range dispatch first
  const int per_bm = 8 * nb;
  const int w = blockIdx.x;
  const int bm = 15 - (w / per_bm);
  const int inner = w - (15 - bm) * per_bm;
  const int bn = inner & 7;
  const int zl = inner >> 3;
  const int b = b0 + zl;

  __shared__ __attribute__((aligned(16))) unsigned short As[2][128 * 32];
  __shared__ __attribute__((aligned(16))) unsigned short Bs[2][128 * 32];
  const int tid = threadIdx.x, lane = tid & 63, wave = tid >> 6;
  const int wr = wave >> 1, wc = wave & 1;

  const unsigned short* A = P + (int64_t)zl * p_zstride;
  const unsigned short* Ag = A + (int64_t)(bm * 128 + wave * 32 + (lane >> 2)) * Sn + (lane & 3) * 8;
  const unsigned short* Bg = VTb + (int64_t)(bn * 128 + wave * 32 + (lane >> 2)) * (Bn * Sn)
                             + (int64_t)b * Sn + (lane & 3) * 8;

  f32x4 zero = {0.f, 0.f, 0.f, 0.f};
  f32x4 acc[4][4];
#pragma unroll
  for (int m = 0; m < 4; m++)
#pragma unroll
    for (int n = 0; n < 4; n++) acc[m][n] = zero;

  auto stage = [&](int kt, int buf) {
    const int k0 = kt << 5;
    char* a = (char*)As[buf] + wave * 2048;
    char* b2 = (char*)Bs[buf] + wave * 2048;
    gload16(Ag + k0, a);
    gload16(Ag + k0 + 16 * Sn, a + 1024);
    gload16(Bg + k0, b2);
    gload16(Bg + k0 + (int64_t)16 * (Bn * Sn), b2 + 1024);
  };

  const int nkt = (bm + 1) * 4;  // causal: k < (bm+1)*128
  stage(0, 0);
  __syncthreads();
  for (int kt = 0; kt < nkt; ++kt) {
    const int buf = kt & 1;
    if (kt + 1 < nkt) stage(kt + 1, buf ^ 1);
    const short* Ap = (const short*)As[buf];
    const short* Bp = (const short*)Bs[buf];
    const int ko = (lane >> 4) * 8;
    short8 af[4], bfv[4];
#pragma unroll
    for (int m = 0; m < 4; m++)
      af[m] = *(const short8*)(Ap + (wr * 64 + m * 16 + (lane & 15)) * 32 + ko);
#pragma unroll
    for (int n = 0; n < 4; n++)
      bfv[n] = *(const short8*)(Bp + (wc * 64 + n * 16 + (lane & 15)) * 32 + ko);
#pragma unroll
    for (int m = 0; m < 4; m++)
#pragma unroll
      for (int n = 0; n < 4; n++)
        acc[m][n] = __builtin_amdgcn_mfma_f32_16x16x32_bf16(af[m], bfv[n], acc[m][n], 0, 0, 0);
    __syncthreads();
  }

#pragma unroll
  for (int m = 0; m < 4; m++) {
    const int r0 = bm * 128 + wr * 64 + m * 16 + ((lane >> 4) << 2);
#pragma unroll
    for (int j = 0; j < 4; j++) {
      const int q = r0 + j;
      const float linv = 1.0f / l[(int64_t)b * Sn + q];
#pragma unroll
      for (int n = 0; n < 4; n++) {
        const int d = bn * 128 + wc * 64 + n * 16 + (lane & 15);
        Out[(int64_t)b * Sn * Hn + (int64_t)q * Hn + d] = acc[m][n][j] * linv;
      }
    }
  }
}

// ---------------- host launch ----------------
extern "C" void kernel_launch(void* const* d_in, const int* in_sizes, int n_in,
                              void* d_out, int out_size, void* d_ws, size_t ws_size,
                              hipStream_t stream) {
  const float* x  = (const float*)d_in[0];
  // d_in[1] = attention_mask (causal tril by construction) — not needed
  const float* wq = (const float*)d_in[2];
  const float* wk = (const float*)d_in[3];
  const float* wv = (const float*)d_in[4];
  float* out = (float*)d_out;
  char* ws = (char*)d_ws;

  const int64_t MiB = 1ll << 20;
  unsigned short* xb = (unsigned short*)(ws);              // 16 MiB
  unsigned short* wb = (unsigned short*)(ws + 16 * MiB);   // 6 MiB (wq|wk|wv)
  float* l           = (float*)(ws + 22 * MiB);            // 32 KiB
  unsigned short* Qb = (unsigned short*)(ws + 23 * MiB);   // 16 MiB
  unsigned short* Kb = (unsigned short*)(ws + 39 * MiB);   // 16 MiB
  unsigned short* VT = (unsigned short*)(ws + 55 * MiB);   // 16 MiB  [Hn][Bn*Sn]
  unsigned short* P  = (unsigned short*)(ws + 71 * MiB);   // up to 32 MiB (bf16 [nb][S][S])

  // 1. fp32 -> bf16
  cvt_kernel<<<2048, 256, 0, stream>>>(x, wq, wk, wv, xb, wb);
  // 2. Q,K projection: M=8192, N=2048 (wq|wk), K=1024, routed outputs (1024 blocks)
  gemm_bt_dbuf_kernel<<<1024, 256, 0, stream>>>(
      xb, 1024, wb, 1024, Qb, Kb, 1024, 1024, 63, 6, 1024);
  // 3. V^T = Wv * x^T: M=1024 (d), N=8192 (b,s), K=1024 (512 blocks)
  gemm_bt_dbuf_kernel<<<512, 256, 0, stream>>>(
      wb + 2 * 1024 * 1024, 1024, xb, 1024, VT, VT, 1 << 30, 8192, 7, 3, 1024);

  // 4-6. per-batch-group: P = exp(QK^T*scale), l = rowsum(P), O = (P V)/l
  int nb = 1;
  if (ws_size >= 103ull * MiB) nb = 4;
  else if (ws_size >= 87ull * MiB) nb = 2;
  for (int b0 = 0; b0 < Bn; b0 += nb) {
    scores_exp_kernel<<<136 * nb, 256, 0, stream>>>(
        Qb, Kb, P, (int64_t)Sn * Sn, b0);
    rowsum_kernel<<<nb * 512, 256, 0, stream>>>(P, l, b0, nb);
    pv_gemm_kernel<<<16 * 8 * nb, 256, 0, stream>>>(
        P, (int64_t)Sn * Sn, VT, l, out, b0, nb);
  }
}